// Round 1
// baseline (259.155 us; speedup 1.0000x reference)
//
#include <hip/hip_runtime.h>
#include <math.h>

#define BB 8
#define TT 4096
#define FF 1024
#define TS 64              // t-splits in kernel1
#define TCHUNK (TT / TS)   // 64 timesteps per split

// ---------------------------------------------------------------------------
// Kernel 1: partial masked column sums.  part[b, ts, f] = sum_{t in chunk, mask} x[b,t,f]
// grid: (FF/256, TS, BB), block: 256
// ---------------------------------------------------------------------------
__global__ __launch_bounds__(256) void k1_partial(const float* __restrict__ x,
                                                  const int* __restrict__ mask,
                                                  float* __restrict__ part) {
    int f  = blockIdx.x * 256 + threadIdx.x;
    int ts = blockIdx.y;
    int b  = blockIdx.z;
    const float* xb = x + ((size_t)b * TT + (size_t)ts * TCHUNK) * FF + f;
    const int*   mb = mask + (size_t)b * TT + (size_t)ts * TCHUNK;
    float acc = 0.f;
    for (int t = 0; t < TCHUNK; ++t) {
        if (mb[t]) acc += xb[(size_t)t * FF];   // wave-uniform branch
    }
    part[((size_t)b * TS + ts) * FF + f] = acc;
}

// ---------------------------------------------------------------------------
// Kernel 2: per-batch stats.  kc[b,f] = k - mean_f(k);  kd[b] = ||kc||; skc[b] = sum_f kc
// grid: BB, block: 1024 (one thread per f)
// ---------------------------------------------------------------------------
__global__ __launch_bounds__(1024) void k2_stats(const float* __restrict__ part,
                                                 const int* __restrict__ mask,
                                                 float* __restrict__ kc,
                                                 float* __restrict__ kd_arr,
                                                 float* __restrict__ skc_arr) {
    __shared__ float redA[16];
    __shared__ float redB[16];
    __shared__ float Lsh, meansh;

    int b    = blockIdx.x;
    int tid  = threadIdx.x;
    int wave = tid >> 6;
    int lane = tid & 63;

    // ---- valid-length L ----
    int cnt = 0;
    for (int t = tid; t < TT; t += 1024) cnt += mask[(size_t)b * TT + t];
    float fc = (float)cnt;
    #pragma unroll
    for (int off = 32; off; off >>= 1) fc += __shfl_xor(fc, off);
    if (lane == 0) redA[wave] = fc;
    __syncthreads();
    if (tid == 0) {
        float s = 0.f;
        for (int i = 0; i < 16; ++i) s += redA[i];
        Lsh = s;
    }
    __syncthreads();
    float L = Lsh;

    // ---- k[f] = sum of partials / L ----
    float s = 0.f;
    for (int ts = 0; ts < TS; ++ts) s += part[((size_t)b * TS + ts) * FF + tid];
    float k = s / L;

    // ---- mean over F ----
    float m = k;
    #pragma unroll
    for (int off = 32; off; off >>= 1) m += __shfl_xor(m, off);
    __syncthreads();                 // done with redA reads above
    if (lane == 0) redA[wave] = m;
    __syncthreads();
    if (tid == 0) {
        float t = 0.f;
        for (int i = 0; i < 16; ++i) t += redA[i];
        meansh = t * (1.0f / FF);
    }
    __syncthreads();
    float kcv = k - meansh;
    kc[(size_t)b * FF + tid] = kcv;

    // ---- ||kc|| and sum(kc) ----
    float a  = kcv * kcv;
    float c2 = kcv;
    #pragma unroll
    for (int off = 32; off; off >>= 1) {
        a  += __shfl_xor(a, off);
        c2 += __shfl_xor(c2, off);
    }
    __syncthreads();                 // done with redA/meansh reads
    if (lane == 0) { redA[wave] = a; redB[wave] = c2; }
    __syncthreads();
    if (tid == 0) {
        float sa = 0.f, sc = 0.f;
        for (int i = 0; i < 16; ++i) { sa += redA[i]; sc += redB[i]; }
        kd_arr[b]  = sqrtf(sa);
        skc_arr[b] = sc;
    }
}

// ---------------------------------------------------------------------------
// Kernel 3: per-row gate + apply.  One block per (b,t), 256 threads, float4/thread.
// grid: (TT, BB), block: 256
// ---------------------------------------------------------------------------
__global__ __launch_bounds__(256) void k3_apply(const float* __restrict__ x,
                                                const int* __restrict__ mask,
                                                const float* __restrict__ kc,
                                                const float* __restrict__ kd_arr,
                                                const float* __restrict__ skc_arr,
                                                float* __restrict__ out) {
    int t   = blockIdx.x;
    int b   = blockIdx.y;
    int tid = threadIdx.x;
    size_t row = ((size_t)b * TT + t) * FF;
    const float4* xr   = (const float4*)(x + row);
    float4*       outr = (float4*)(out + row);

    int mval = mask[(size_t)b * TT + t];
    if (mval == 0) {                       // padded row: zero output
        outr[tid] = make_float4(0.f, 0.f, 0.f, 0.f);
        return;
    }

    float4 xv = xr[tid];
    const float4* kcr = (const float4*)(kc + (size_t)b * FF);
    float4 kv = kcr[tid];

    float s1 = xv.x + xv.y + xv.z + xv.w;
    float s2 = xv.x * xv.x + xv.y * xv.y + xv.z * xv.z + xv.w * xv.w;
    float s3 = xv.x * kv.x + xv.y * kv.y + xv.z * kv.z + xv.w * kv.w;
    #pragma unroll
    for (int off = 32; off; off >>= 1) {
        s1 += __shfl_xor(s1, off);
        s2 += __shfl_xor(s2, off);
        s3 += __shfl_xor(s3, off);
    }

    __shared__ float r1[4], r2[4], r3[4];
    __shared__ float Ash;
    int wave = tid >> 6, lane = tid & 63;
    if (lane == 0) { r1[wave] = s1; r2[wave] = s2; r3[wave] = s3; }
    __syncthreads();
    if (tid == 0) {
        float S1 = r1[0] + r1[1] + r1[2] + r1[3];
        float S2 = r2[0] + r2[1] + r2[2] + r2[3];
        float S3 = r3[0] + r3[1] + r3[2] + r3[3];
        float mean = S1 * (1.0f / FF);
        float num  = S3 - mean * skc_arr[b];          // sum(x_c * k_c)
        float qd2  = S2 - S1 * S1 * (1.0f / FF);      // sum(x_c^2)
        float qd   = sqrtf(fmaxf(qd2, 0.f));
        float C    = num / (qd * kd_arr[b]);
        Ash = 1.0f / (1.0f + __expf(C));              // 1 - sigmoid(C)
    }
    __syncthreads();
    float A = Ash;
    float4 o;
    o.x = xv.x * A; o.y = xv.y * A; o.z = xv.z * A; o.w = xv.w * A;
    outr[tid] = o;
}

// ---------------------------------------------------------------------------
extern "C" void kernel_launch(void* const* d_in, const int* in_sizes, int n_in,
                              void* d_out, int out_size, void* d_ws, size_t ws_size,
                              hipStream_t stream) {
    const float* x    = (const float*)d_in[0];
    const int*   mask = (const int*)d_in[1];
    float*       out  = (float*)d_out;

    // workspace layout (floats): part[B*TS*F] | kc[B*F] | kd[B] | skc[B]
    float* part = (float*)d_ws;
    float* kc   = part + (size_t)BB * TS * FF;
    float* kd   = kc + (size_t)BB * FF;
    float* skc  = kd + BB;

    k1_partial<<<dim3(FF / 256, TS, BB), 256, 0, stream>>>(x, mask, part);
    k2_stats<<<BB, 1024, 0, stream>>>(part, mask, kc, kd, skc);
    k3_apply<<<dim3(TT, BB), 256, 0, stream>>>(x, mask, kc, kd, skc, out);
}

// Round 2
// 254.419 us; speedup vs baseline: 1.0186x; 1.0186x over previous
//
#include <hip/hip_runtime.h>
#include <math.h>

#define BB 8
#define TT 4096
#define FF 1024
#define F4 (FF / 4)        // 256 float4 per row
#define TS 64              // t-splits in kernel1
#define TCHUNK (TT / TS)   // 64 timesteps per split

// ---------------------------------------------------------------------------
// Kernel 1: partial masked column sums, branch-free, float4.
// part[b, ts, f] = sum_{t in chunk} mask[b,t] * x[b,t,f]
// grid: (TS, BB), block: 256 (each thread owns 4 consecutive f's)
// ---------------------------------------------------------------------------
__global__ __launch_bounds__(256) void k1_partial(const float4* __restrict__ x4,
                                                  const int* __restrict__ mask,
                                                  float4* __restrict__ part4) {
    int ts  = blockIdx.x;
    int b   = blockIdx.y;
    int tid = threadIdx.x;

    __shared__ float msh[TCHUNK];
    if (tid < TCHUNK) msh[tid] = (float)mask[(size_t)b * TT + (size_t)ts * TCHUNK + tid];
    __syncthreads();

    const float4* xb = x4 + ((size_t)b * TT + (size_t)ts * TCHUNK) * F4 + tid;
    float4 acc = make_float4(0.f, 0.f, 0.f, 0.f);
    #pragma unroll 8
    for (int t = 0; t < TCHUNK; ++t) {
        float4 v = xb[(size_t)t * F4];        // independent, pipelined loads
        float  m = msh[t];                    // LDS broadcast, free
        acc.x = fmaf(m, v.x, acc.x);
        acc.y = fmaf(m, v.y, acc.y);
        acc.z = fmaf(m, v.z, acc.z);
        acc.w = fmaf(m, v.w, acc.w);
    }
    part4[((size_t)b * TS + ts) * F4 + tid] = acc;
}

// ---------------------------------------------------------------------------
// Kernel 2: per-batch stats. kc[b,f] = k - mean_f(k); kd[b] = ||kc||; skc[b] = sum(kc)
// grid: BB, block: 1024 (one thread per f)
// ---------------------------------------------------------------------------
__global__ __launch_bounds__(1024) void k2_stats(const float* __restrict__ part,
                                                 const int* __restrict__ mask,
                                                 float* __restrict__ kc,
                                                 float* __restrict__ kd_arr,
                                                 float* __restrict__ skc_arr) {
    __shared__ float redA[16];
    __shared__ float redB[16];
    __shared__ float Lsh, meansh;

    int b    = blockIdx.x;
    int tid  = threadIdx.x;
    int wave = tid >> 6;
    int lane = tid & 63;

    // ---- valid-length L ----
    int cnt = 0;
    #pragma unroll
    for (int i = 0; i < 4; ++i) cnt += mask[(size_t)b * TT + tid + i * 1024];
    float fc = (float)cnt;
    #pragma unroll
    for (int off = 32; off; off >>= 1) fc += __shfl_xor(fc, off);
    if (lane == 0) redA[wave] = fc;
    __syncthreads();
    if (tid == 0) {
        float s = 0.f;
        for (int i = 0; i < 16; ++i) s += redA[i];
        Lsh = s;
    }
    __syncthreads();
    float L = Lsh;

    // ---- k[f] = sum of partials / L ----
    float s = 0.f;
    #pragma unroll 8
    for (int ts = 0; ts < TS; ++ts) s += part[((size_t)b * TS + ts) * FF + tid];
    float k = s / L;

    // ---- mean over F ----
    float m = k;
    #pragma unroll
    for (int off = 32; off; off >>= 1) m += __shfl_xor(m, off);
    __syncthreads();
    if (lane == 0) redA[wave] = m;
    __syncthreads();
    if (tid == 0) {
        float t = 0.f;
        for (int i = 0; i < 16; ++i) t += redA[i];
        meansh = t * (1.0f / FF);
    }
    __syncthreads();
    float kcv = k - meansh;
    kc[(size_t)b * FF + tid] = kcv;

    // ---- ||kc|| and sum(kc) ----
    float a  = kcv * kcv;
    float c2 = kcv;
    #pragma unroll
    for (int off = 32; off; off >>= 1) {
        a  += __shfl_xor(a, off);
        c2 += __shfl_xor(c2, off);
    }
    __syncthreads();
    if (lane == 0) { redA[wave] = a; redB[wave] = c2; }
    __syncthreads();
    if (tid == 0) {
        float sa = 0.f, sc = 0.f;
        for (int i = 0; i < 16; ++i) { sa += redA[i]; sc += redB[i]; }
        kd_arr[b]  = sqrtf(sa);
        skc_arr[b] = sc;
    }
}

// ---------------------------------------------------------------------------
// Kernel 3: per-row gate + apply. One block per (b,t), 256 threads, float4/thread.
// Single barrier: every thread sums the 4 per-wave partials and computes A.
// grid: (TT, BB), block: 256
// ---------------------------------------------------------------------------
__global__ __launch_bounds__(256) void k3_apply(const float4* __restrict__ x4,
                                                const int* __restrict__ mask,
                                                const float4* __restrict__ kc4,
                                                const float* __restrict__ kd_arr,
                                                const float* __restrict__ skc_arr,
                                                float4* __restrict__ out4) {
    int t   = blockIdx.x;
    int b   = blockIdx.y;
    int tid = threadIdx.x;
    size_t row = ((size_t)b * TT + t) * F4;

    if (mask[(size_t)b * TT + t] == 0) {          // padded row: zero output
        out4[row + tid] = make_float4(0.f, 0.f, 0.f, 0.f);
        return;
    }

    float4 xv = x4[row + tid];
    float4 kv = kc4[(size_t)b * F4 + tid];        // L1/L2-hot, 4 KB per batch

    float s1 = xv.x + xv.y + xv.z + xv.w;
    float s2 = xv.x * xv.x + xv.y * xv.y + xv.z * xv.z + xv.w * xv.w;
    float s3 = xv.x * kv.x + xv.y * kv.y + xv.z * kv.z + xv.w * kv.w;
    #pragma unroll
    for (int off = 32; off; off >>= 1) {
        s1 += __shfl_xor(s1, off);
        s2 += __shfl_xor(s2, off);
        s3 += __shfl_xor(s3, off);
    }

    __shared__ float r1[4], r2[4], r3[4];
    int wave = tid >> 6, lane = tid & 63;
    if (lane == 0) { r1[wave] = s1; r2[wave] = s2; r3[wave] = s3; }
    __syncthreads();

    float S1 = r1[0] + r1[1] + r1[2] + r1[3];
    float S2 = r2[0] + r2[1] + r2[2] + r2[3];
    float S3 = r3[0] + r3[1] + r3[2] + r3[3];
    float mean = S1 * (1.0f / FF);
    float num  = S3 - mean * skc_arr[b];          // sum(x_c * k_c)
    float qd2  = S2 - S1 * S1 * (1.0f / FF);      // sum(x_c^2)
    float qd   = sqrtf(fmaxf(qd2, 0.f));
    float C    = num / (qd * kd_arr[b]);
    float A    = 1.0f / (1.0f + __expf(C));       // 1 - sigmoid(C)

    float4 o;
    o.x = xv.x * A; o.y = xv.y * A; o.z = xv.z * A; o.w = xv.w * A;
    out4[row + tid] = o;
}

// ---------------------------------------------------------------------------
extern "C" void kernel_launch(void* const* d_in, const int* in_sizes, int n_in,
                              void* d_out, int out_size, void* d_ws, size_t ws_size,
                              hipStream_t stream) {
    const float* x    = (const float*)d_in[0];
    const int*   mask = (const int*)d_in[1];
    float*       out  = (float*)d_out;

    // workspace layout (floats): part[B*TS*F] | kc[B*F] | kd[B] | skc[B]
    float* part = (float*)d_ws;
    float* kc   = part + (size_t)BB * TS * FF;
    float* kd   = kc + (size_t)BB * FF;
    float* skc  = kd + BB;

    k1_partial<<<dim3(TS, BB), 256, 0, stream>>>((const float4*)x, mask, (float4*)part);
    k2_stats<<<BB, 1024, 0, stream>>>(part, mask, kc, kd, skc);
    k3_apply<<<dim3(TT, BB), 256, 0, stream>>>((const float4*)x, mask, (const float4*)kc,
                                               kd, skc, (float4*)out);
}

// Round 4
// 254.223 us; speedup vs baseline: 1.0194x; 1.0008x over previous
//
#include <hip/hip_runtime.h>
#include <math.h>

#define BB 8
#define TT 4096
#define FF 1024
#define F4 (FF / 4)        // 256 float4 per row
#define TS 128             // t-splits in kernel1
#define TCHUNK (TT / TS)   // 32 timesteps per split

typedef float vfloat4 __attribute__((ext_vector_type(4)));   // clang-native, ok for nontemporal builtins

// ---------------------------------------------------------------------------
// Kernel 1: partial masked column sums, branch-free, float4.
// part[b, ts, f] = sum_{t in chunk} mask[b,t] * x[b,t,f]
// grid: (TS, BB), block: 256 (each thread owns 4 consecutive f's)
// ---------------------------------------------------------------------------
__global__ __launch_bounds__(256) void k1_partial(const float4* __restrict__ x4,
                                                  const int* __restrict__ mask,
                                                  float4* __restrict__ part4) {
    int ts  = blockIdx.x;
    int b   = blockIdx.y;
    int tid = threadIdx.x;

    __shared__ float msh[TCHUNK];
    if (tid < TCHUNK) msh[tid] = (float)mask[(size_t)b * TT + (size_t)ts * TCHUNK + tid];
    __syncthreads();

    const float4* xb = x4 + ((size_t)b * TT + (size_t)ts * TCHUNK) * F4 + tid;
    float4 acc = make_float4(0.f, 0.f, 0.f, 0.f);
    #pragma unroll 8
    for (int t = 0; t < TCHUNK; ++t) {
        float4 v = xb[(size_t)t * F4];        // independent, pipelined loads
        float  m = msh[t];                    // LDS broadcast
        acc.x = fmaf(m, v.x, acc.x);
        acc.y = fmaf(m, v.y, acc.y);
        acc.z = fmaf(m, v.z, acc.z);
        acc.w = fmaf(m, v.w, acc.w);
    }
    part4[((size_t)b * TS + ts) * F4 + tid] = acc;
}

// ---------------------------------------------------------------------------
// Kernel 2: per-batch stats. kc[b,f] = k - mean_f(k); kd[b] = ||kc||; skc[b] = sum(kc)
// grid: BB, block: 1024 (one thread per f)
// ---------------------------------------------------------------------------
__global__ __launch_bounds__(1024) void k2_stats(const float* __restrict__ part,
                                                 const int* __restrict__ mask,
                                                 float* __restrict__ kc,
                                                 float* __restrict__ kd_arr,
                                                 float* __restrict__ skc_arr) {
    __shared__ float redA[16];
    __shared__ float redB[16];
    __shared__ float Lsh, meansh;

    int b    = blockIdx.x;
    int tid  = threadIdx.x;
    int wave = tid >> 6;
    int lane = tid & 63;

    // ---- valid-length L ----
    int cnt = 0;
    #pragma unroll
    for (int i = 0; i < 4; ++i) cnt += mask[(size_t)b * TT + tid + i * 1024];
    float fc = (float)cnt;
    #pragma unroll
    for (int off = 32; off; off >>= 1) fc += __shfl_xor(fc, off);
    if (lane == 0) redA[wave] = fc;
    __syncthreads();
    if (tid == 0) {
        float s = 0.f;
        for (int i = 0; i < 16; ++i) s += redA[i];
        Lsh = s;
    }
    __syncthreads();
    float L = Lsh;

    // ---- k[f] = sum of partials / L ----
    float s = 0.f;
    #pragma unroll 8
    for (int ts = 0; ts < TS; ++ts) s += part[((size_t)b * TS + ts) * FF + tid];
    float k = s / L;

    // ---- mean over F ----
    float m = k;
    #pragma unroll
    for (int off = 32; off; off >>= 1) m += __shfl_xor(m, off);
    __syncthreads();
    if (lane == 0) redA[wave] = m;
    __syncthreads();
    if (tid == 0) {
        float t = 0.f;
        for (int i = 0; i < 16; ++i) t += redA[i];
        meansh = t * (1.0f / FF);
    }
    __syncthreads();
    float kcv = k - meansh;
    kc[(size_t)b * FF + tid] = kcv;

    // ---- ||kc|| and sum(kc) ----
    float a  = kcv * kcv;
    float c2 = kcv;
    #pragma unroll
    for (int off = 32; off; off >>= 1) {
        a  += __shfl_xor(a, off);
        c2 += __shfl_xor(c2, off);
    }
    __syncthreads();
    if (lane == 0) { redA[wave] = a; redB[wave] = c2; }
    __syncthreads();
    if (tid == 0) {
        float sa = 0.f, sc = 0.f;
        for (int i = 0; i < 16; ++i) { sa += redA[i]; sc += redB[i]; }
        kd_arr[b]  = sqrtf(sa);
        skc_arr[b] = sc;
    }
}

// ---------------------------------------------------------------------------
// Kernel 3: wave-per-row gate + apply. 64 lanes cover one 1024-f row with
// 4 strided-coalesced float4 loads each. Pure shuffle reduction — no LDS,
// no barriers. 4 rows per 256-thread block. Nontemporal out stores keep x
// L3-resident for the second pass. grid: (TT/4, BB), block: 256
// ---------------------------------------------------------------------------
__global__ __launch_bounds__(256) void k3_apply(const float4* __restrict__ x4,
                                                const int* __restrict__ mask,
                                                const float4* __restrict__ kc4,
                                                const float* __restrict__ kd_arr,
                                                const float* __restrict__ skc_arr,
                                                float4* __restrict__ out4) {
    int wave = threadIdx.x >> 6;
    int lane = threadIdx.x & 63;
    int t    = blockIdx.x * 4 + wave;
    int b    = blockIdx.y;
    size_t row = ((size_t)b * TT + t) * F4;

    vfloat4* orow = (vfloat4*)(out4 + row);
    if (mask[(size_t)b * TT + t] == 0) {          // padded row: zero output
        vfloat4 z = (vfloat4)(0.f);
        #pragma unroll
        for (int j = 0; j < 4; ++j)
            __builtin_nontemporal_store(z, orow + lane + 64 * j);
        return;
    }

    const float4* xrow = x4 + row;
    const float4* krow = kc4 + (size_t)b * F4;
    float4 xv[4], kv[4];
    #pragma unroll
    for (int j = 0; j < 4; ++j) {
        xv[j] = xrow[lane + 64 * j];              // 1 KB coalesced per load
        kv[j] = krow[lane + 64 * j];              // L2-hot (4 KB per batch)
    }

    float s1 = 0.f, s2 = 0.f, s3 = 0.f;
    #pragma unroll
    for (int j = 0; j < 4; ++j) {
        s1 += xv[j].x + xv[j].y + xv[j].z + xv[j].w;
        s2 = fmaf(xv[j].x, xv[j].x, fmaf(xv[j].y, xv[j].y,
             fmaf(xv[j].z, xv[j].z, fmaf(xv[j].w, xv[j].w, s2))));
        s3 = fmaf(xv[j].x, kv[j].x, fmaf(xv[j].y, kv[j].y,
             fmaf(xv[j].z, kv[j].z, fmaf(xv[j].w, kv[j].w, s3))));
    }
    #pragma unroll
    for (int off = 32; off; off >>= 1) {
        s1 += __shfl_xor(s1, off);
        s2 += __shfl_xor(s2, off);
        s3 += __shfl_xor(s3, off);
    }

    float mean = s1 * (1.0f / FF);
    float num  = s3 - mean * skc_arr[b];          // sum(x_c * k_c)
    float qd2  = s2 - s1 * s1 * (1.0f / FF);      // sum(x_c^2)
    float qd   = sqrtf(fmaxf(qd2, 0.f));
    float C    = num / (qd * kd_arr[b]);
    float A    = 1.0f / (1.0f + __expf(C));       // 1 - sigmoid(C)

    #pragma unroll
    for (int j = 0; j < 4; ++j) {
        vfloat4 o;
        o.x = xv[j].x * A; o.y = xv[j].y * A;
        o.z = xv[j].z * A; o.w = xv[j].w * A;
        __builtin_nontemporal_store(o, orow + lane + 64 * j);
    }
}

// ---------------------------------------------------------------------------
extern "C" void kernel_launch(void* const* d_in, const int* in_sizes, int n_in,
                              void* d_out, int out_size, void* d_ws, size_t ws_size,
                              hipStream_t stream) {
    const float* x    = (const float*)d_in[0];
    const int*   mask = (const int*)d_in[1];
    float*       out  = (float*)d_out;

    // workspace layout (floats): part[B*TS*F] | kc[B*F] | kd[B] | skc[B]
    float* part = (float*)d_ws;
    float* kc   = part + (size_t)BB * TS * FF;
    float* kd   = kc + (size_t)BB * FF;
    float* skc  = kd + BB;

    k1_partial<<<dim3(TS, BB), 256, 0, stream>>>((const float4*)x, mask, (float4*)part);
    k2_stats<<<BB, 1024, 0, stream>>>(part, mask, kc, kd, skc);
    k3_apply<<<dim3(TT / 4, BB), 256, 0, stream>>>((const float4*)x, mask, (const float4*)kc,
                                                   kd, skc, (float4*)out);
}